// Round 16
// baseline (613.969 us; speedup 1.0000x reference)
//
#include <hip/hip_runtime.h>
#include <hip/hip_fp16.h>
#include <math.h>

#define NN 50000
#define NE 800000
#define ETOT (NE + NN)
#define HID 64
#define CH 256          // HEADS*HID
#define IND 16
#define LN_EPS 1e-5f
#define NSLOPE 0.2f
#define ELLW 64         // ELL width
#define EB ((ETOT + 255) / 256)   // edge chunks
#define PB ((NN + 31) / 32)       // proj tile blocks
#define AGB (((NN + 255) / 256) * 8)

__device__ __forceinline__ float lrelu(float v){ return v > 0.f ? v : NSLOPE * v; }
__device__ __forceinline__ float sigf(float v){ return 1.f / (1.f + __expf(-v)); }

// xphP layout: [group g][node][c' 0..7][head 0..3] fp16 (64 B per node per group).
// group g owns output channels 8g..8g+8; its slice is NN*64 B = 3.2 MB -> L2-resident
// on the XCD that processes group g (k_agg maps bid%8 = g -> constant XCD).

// ---------------- fused projection-1 + XCD-partitioned ELL build ----------------

__global__ __launch_bounds__(256) void k_build_proj1(const int* __restrict__ ei,
    int* __restrict__ deg, unsigned short* __restrict__ colE,
    const float* __restrict__ h, const float* __restrict__ w,
    const float* __restrict__ asr, const float* __restrict__ adr,
    __half* __restrict__ xphP, float* __restrict__ es, float* __restrict__ ed){
  __shared__ float w_s[IND * CH];
  __shared__ float h_s[IND][36];
  __shared__ float as_s[CH], ad_s[CH];
  const int t = threadIdx.x;

  if (blockIdx.x >= PB){
    // ELL build, partitioned by dst&7 (one XCD owns each node's colE lines)
    const int bb = blockIdx.x - PB;
    const int part = bb & 7;
    const int e = (bb >> 3) * 256 + t;
    if (e < ETOT){
      const int d = (e < NE) ? ei[NE + e] : (e - NE);
      if ((d & 7) == part){
        const int s = (e < NE) ? ei[e] : d;
        const int slot = atomicAdd(&deg[d], 1);
        if (slot < ELLW) colE[d * ELLW + slot] = (unsigned short)s;
      }
    }
    return;
  }

  // proj1 (one 32-node tile per block)
  const int tile = blockIdx.x * 32;
  for (int i = t; i < IND * CH; i += 256) w_s[i] = w[i];
  as_s[t] = asr[t]; ad_s[t] = adr[t];
  for (int i = t; i < 32 * IND; i += 256){
    int n = i / IND, k = i % IND;
    int nn = tile + n;
    h_s[k][n] = (nn < NN) ? h[nn * IND + k] : 0.f;
  }
  __syncthreads();

  const int wv = t >> 6, l = t & 63;
  const int tc = l & 31, th = l >> 5;
  const int g = wv * 2 + th;
  const int c0 = tc * 4;
  const int hA = tc >> 4;               // head of first quad (== c0>>6)

  float acc[4][8];
  #pragma unroll
  for (int j = 0; j < 4; ++j)
    #pragma unroll
    for (int i = 0; i < 8; ++i) acc[j][i] = 0.f;

  #pragma unroll 4
  for (int k = 0; k < IND; ++k){
    const float4 wa = *(const float4*)&w_s[k * CH + c0];
    const float4 wb = *(const float4*)&w_s[k * CH + c0 + 128];
    const float4 hv = *(const float4*)&h_s[k][g * 4];
    const float hj0 = hv.x, hj1 = hv.y, hj2 = hv.z, hj3 = hv.w;
    #define STEP(j, hjv) \
      acc[j][0] = fmaf(hjv, wa.x, acc[j][0]); \
      acc[j][1] = fmaf(hjv, wa.y, acc[j][1]); \
      acc[j][2] = fmaf(hjv, wa.z, acc[j][2]); \
      acc[j][3] = fmaf(hjv, wa.w, acc[j][3]); \
      acc[j][4] = fmaf(hjv, wb.x, acc[j][4]); \
      acc[j][5] = fmaf(hjv, wb.y, acc[j][5]); \
      acc[j][6] = fmaf(hjv, wb.z, acc[j][6]); \
      acc[j][7] = fmaf(hjv, wb.w, acc[j][7]);
    STEP(0, hj0) STEP(1, hj1) STEP(2, hj2) STEP(3, hj3)
    #undef STEP
  }

  const int oc = c0 & 63;               // output channel of quad (mult of 4)
  const int gI = oc >> 3;               // channel group
  const int cp = oc & 7;                // 0 or 4
  #pragma unroll
  for (int j = 0; j < 4; ++j){
    const int nj = tile + g * 4 + j;
    float pa = 0.f, pb = 0.f, qa = 0.f, qb = 0.f;
    #pragma unroll
    for (int i = 0; i < 4; ++i){
      pa = fmaf(acc[j][i],     as_s[c0 + i],       pa);
      pb = fmaf(acc[j][4 + i], as_s[c0 + 128 + i], pb);
      qa = fmaf(acc[j][i],     ad_s[c0 + i],       qa);
      qb = fmaf(acc[j][4 + i], ad_s[c0 + 128 + i], qb);
    }
    #pragma unroll
    for (int d = 8; d; d >>= 1){
      pa += __shfl_xor(pa, d); pb += __shfl_xor(pb, d);
      qa += __shfl_xor(qa, d); qb += __shfl_xor(qb, d);
    }
    if (nj < NN){
      __half* wbase = &xphP[(((size_t)gI * NN + nj) * 8 + cp) * 4];
      #pragma unroll
      for (int i = 0; i < 4; ++i){
        wbase[i * 4 + hA]     = __float2half(acc[j][i]);      // head hA
        wbase[i * 4 + hA + 2] = __float2half(acc[j][4 + i]);  // head hA+2
      }
      if ((tc & 15) == 0){
        es[nj * 4 + hA]     = pa;
        es[nj * 4 + hA + 2] = pb;
        ed[nj * 4 + hA]     = qa;
        ed[nj * 4 + hA + 2] = qb;
      }
    }
  }
}

// ---------------- projection-2 (K=64, fp16 LDS weights, fused LN0+ReLU) ----------------

__global__ __launch_bounds__(256) void k_proj2(const float* __restrict__ hP,
    const float* __restrict__ w, const float* __restrict__ asr,
    const float* __restrict__ adr, const float* __restrict__ lng,
    const float* __restrict__ lnb, __half* __restrict__ xphP,
    float* __restrict__ es, float* __restrict__ ed){
  __shared__ __half w_sh[HID * CH];     // 32 KB
  __shared__ float h_s[HID][36];
  __shared__ float as_s[CH], ad_s[CH];
  __shared__ float lg_s[64], lb_s[64], mu_s[32], rs_s[32];
  const int t = threadIdx.x;
  for (int i = t; i < HID * CH; i += 256) w_sh[i] = __float2half(w[i]);
  as_s[t] = asr[t]; ad_s[t] = adr[t];
  if (t < 64){ lg_s[t] = lng[t]; lb_s[t] = lnb[t]; }

  const int tile = blockIdx.x * 32;
  for (int i = t; i < 32 * HID; i += 256){
    int n = i >> 6, k = i & 63;
    int nn = tile + n;
    h_s[k][n] = (nn < NN) ? hP[((size_t)(k >> 3) * NN + nn) * 8 + (k & 7)] : 0.f;
  }
  __syncthreads();
  if (t < 32){
    float s = 0.f, q = 0.f;
    for (int k = 0; k < 64; ++k){ const float v = h_s[k][t]; s += v; q += v * v; }
    const float mu = s * (1.f / 64.f);
    mu_s[t] = mu;
    rs_s[t] = rsqrtf(q * (1.f / 64.f) - mu * mu + LN_EPS);
  }
  __syncthreads();
  for (int i = t; i < 32 * 64; i += 256){
    const int k = i >> 5, n = i & 31;
    float v = (h_s[k][n] - mu_s[n]) * rs_s[n] * lg_s[k] + lb_s[k];
    h_s[k][n] = fmaxf(v, 0.f);          // ReLU (layer-1)
  }
  __syncthreads();

  const int wv = t >> 6, l = t & 63;
  const int tc = l & 31, th = l >> 5;
  const int g = wv * 2 + th;
  const int c0 = tc * 4;
  const int hA = tc >> 4;

  float acc[4][8];
  #pragma unroll
  for (int j = 0; j < 4; ++j)
    #pragma unroll
    for (int i = 0; i < 8; ++i) acc[j][i] = 0.f;

  #pragma unroll 4
  for (int k = 0; k < HID; ++k){
    union { uint2 u; __half2 h2[2]; } A, B;
    A.u = *(const uint2*)&w_sh[k * CH + c0];
    B.u = *(const uint2*)&w_sh[k * CH + c0 + 128];
    const float2 a01 = __half22float2(A.h2[0]), a23 = __half22float2(A.h2[1]);
    const float2 b01 = __half22float2(B.h2[0]), b23 = __half22float2(B.h2[1]);
    float4 wa, wb;
    wa.x = a01.x; wa.y = a01.y; wa.z = a23.x; wa.w = a23.y;
    wb.x = b01.x; wb.y = b01.y; wb.z = b23.x; wb.w = b23.y;
    const float4 hv = *(const float4*)&h_s[k][g * 4];
    const float hj0 = hv.x, hj1 = hv.y, hj2 = hv.z, hj3 = hv.w;
    #define STEP(j, hjv) \
      acc[j][0] = fmaf(hjv, wa.x, acc[j][0]); \
      acc[j][1] = fmaf(hjv, wa.y, acc[j][1]); \
      acc[j][2] = fmaf(hjv, wa.z, acc[j][2]); \
      acc[j][3] = fmaf(hjv, wa.w, acc[j][3]); \
      acc[j][4] = fmaf(hjv, wb.x, acc[j][4]); \
      acc[j][5] = fmaf(hjv, wb.y, acc[j][5]); \
      acc[j][6] = fmaf(hjv, wb.z, acc[j][6]); \
      acc[j][7] = fmaf(hjv, wb.w, acc[j][7]);
    STEP(0, hj0) STEP(1, hj1) STEP(2, hj2) STEP(3, hj3)
    #undef STEP
  }

  const int oc = c0 & 63;
  const int gI = oc >> 3;
  const int cp = oc & 7;
  #pragma unroll
  for (int j = 0; j < 4; ++j){
    const int nj = tile + g * 4 + j;
    float pa = 0.f, pb = 0.f, qa = 0.f, qb = 0.f;
    #pragma unroll
    for (int i = 0; i < 4; ++i){
      pa = fmaf(acc[j][i],     as_s[c0 + i],       pa);
      pb = fmaf(acc[j][4 + i], as_s[c0 + 128 + i], pb);
      qa = fmaf(acc[j][i],     ad_s[c0 + i],       qa);
      qb = fmaf(acc[j][4 + i], ad_s[c0 + 128 + i], qb);
    }
    #pragma unroll
    for (int d = 8; d; d >>= 1){
      pa += __shfl_xor(pa, d); pb += __shfl_xor(pb, d);
      qa += __shfl_xor(qa, d); qb += __shfl_xor(qb, d);
    }
    if (nj < NN){
      __half* wbase = &xphP[(((size_t)gI * NN + nj) * 8 + cp) * 4];
      #pragma unroll
      for (int i = 0; i < 4; ++i){
        wbase[i * 4 + hA]     = __float2half(acc[j][i]);
        wbase[i * 4 + hA + 2] = __float2half(acc[j][4 + i]);
      }
      if ((tc & 15) == 0){
        es[nj * 4 + hA]     = pa;
        es[nj * 4 + hA + 2] = pb;
        ed[nj * 4 + hA]     = qa;
        ed[nj * 4 + hA + 2] = qb;
      }
    }
  }
}

// ---------------- channel-sharded GAT aggregate (pre-LN output) ----------------
// bid%8 = channel group -> constant XCD (round-robin dispatch); the group's
// xphP slice (3.2 MB) is L2-resident. Thread-per-node, per-head register acc,
// no LDS / cross-lane. Output: h' = 0.25*sum_h alpha-weighted + bias (LN in consumer).

__global__ __launch_bounds__(256) void k_agg(const __half* __restrict__ xphP,
    const float4* __restrict__ es4, const float4* __restrict__ ed4,
    const int* __restrict__ deg, const unsigned short* __restrict__ colE,
    const float* __restrict__ bias, float* __restrict__ houtP){
  const int g = blockIdx.x & 7;
  const int n = (blockIdx.x >> 3) * 256 + threadIdx.x;
  if (n >= NN) return;
  const int dg = min(deg[n], ELLW);     // >= 1 (self-loop)
  const float4 edn = ed4[n];
  const __half* __restrict__ xb = xphP + (size_t)g * NN * 32;
  float acc[4][8];
  #pragma unroll
  for (int h = 0; h < 4; ++h)
    #pragma unroll
    for (int c = 0; c < 8; ++c) acc[h][c] = 0.f;
  float den0 = 0.f, den1 = 0.f, den2 = 0.f, den3 = 0.f;

  int s = (int)colE[n * ELLW];
  for (int j = 0; j < dg; ++j){
    const int snext = (j + 1 < dg) ? (int)colE[n * ELLW + j + 1] : 0;
    const float4 e = es4[s];
    const uint4* xq = (const uint4*)&xb[(size_t)s * 32];
    const uint4 q0 = xq[0], q1 = xq[1], q2 = xq[2], q3 = xq[3];
    const float p0 = __expf(lrelu(e.x + edn.x));
    const float p1 = __expf(lrelu(e.y + edn.y));
    const float p2 = __expf(lrelu(e.z + edn.z));
    const float p3 = __expf(lrelu(e.w + edn.w));
    den0 += p0; den1 += p1; den2 += p2; den3 += p3;
    #define ACCQ(q, cb) { \
      union { uint4 u; __half2 hh[4]; } U; U.u = q; \
      const float2 f01 = __half22float2(U.hh[0]); \
      const float2 f23 = __half22float2(U.hh[1]); \
      const float2 g01 = __half22float2(U.hh[2]); \
      const float2 g23 = __half22float2(U.hh[3]); \
      acc[0][cb]     = fmaf(p0, f01.x, acc[0][cb]); \
      acc[1][cb]     = fmaf(p1, f01.y, acc[1][cb]); \
      acc[2][cb]     = fmaf(p2, f23.x, acc[2][cb]); \
      acc[3][cb]     = fmaf(p3, f23.y, acc[3][cb]); \
      acc[0][cb + 1] = fmaf(p0, g01.x, acc[0][cb + 1]); \
      acc[1][cb + 1] = fmaf(p1, g01.y, acc[1][cb + 1]); \
      acc[2][cb + 1] = fmaf(p2, g23.x, acc[2][cb + 1]); \
      acc[3][cb + 1] = fmaf(p3, g23.y, acc[3][cb + 1]); }
    ACCQ(q0, 0) ACCQ(q1, 2) ACCQ(q2, 4) ACCQ(q3, 6)
    #undef ACCQ
    s = snext;
  }

  const float i0 = 1.f / den0, i1 = 1.f / den1, i2 = 1.f / den2, i3 = 1.f / den3;
  const float4 bA = *(const float4*)&bias[g * 8];
  const float4 bB = *(const float4*)&bias[g * 8 + 4];
  float o[8];
  #pragma unroll
  for (int c = 0; c < 8; ++c)
    o[c] = 0.25f * (acc[0][c] * i0 + acc[1][c] * i1 + acc[2][c] * i2 + acc[3][c] * i3);
  float4 oA, oB;
  oA.x = o[0] + bA.x; oA.y = o[1] + bA.y; oA.z = o[2] + bA.z; oA.w = o[3] + bA.w;
  oB.x = o[4] + bB.x; oB.y = o[5] + bB.y; oB.z = o[6] + bB.z; oB.w = o[7] + bB.w;
  float* op = houtP + ((size_t)g * NN + n) * 8;
  *(float4*)op       = oA;
  *(float4*)(op + 4) = oB;
}

// ---------------- GRU (h0=0) as register-blocked GEMM, fused LN1 ----------------

#define WTS 196

__global__ __launch_bounds__(256) void k_gru(const float* __restrict__ hP,
    const float* __restrict__ lng, const float* __restrict__ lnb,
    const float* __restrict__ wih, const float* __restrict__ bih,
    const float* __restrict__ bhh, float* __restrict__ tmp){
  __shared__ __half wT[64 * WTS];
  __shared__ float h_s[64][34];
  __shared__ float bi_s[192], bh_s[192];
  __shared__ float lg_s[64], lb_s[64], mu_s[32], rs_s[32];
  const int t = threadIdx.x;
  for (int i = t; i < 192 * 64; i += 256)
    wT[(i & 63) * WTS + (i >> 6)] = __float2half(wih[i]);
  if (t < 192){ bi_s[t] = bih[t]; bh_s[t] = bhh[t]; }
  if (t < 64){ lg_s[t] = lng[t]; lb_s[t] = lnb[t]; }
  const int col = t & 15, gg = t >> 4;
  const int c0 = col * 4;

  for (int tile = blockIdx.x * 32; tile < NN; tile += gridDim.x * 32){
    __syncthreads();
    for (int i = t; i < 32 * 64; i += 256){
      int nidx = i >> 6, k = i & 63;
      int nn = tile + nidx;
      h_s[k][nidx] = (nn < NN) ? hP[((size_t)(k >> 3) * NN + nn) * 8 + (k & 7)] : 0.f;
    }
    __syncthreads();
    if (t < 32){
      float s = 0.f, q = 0.f;
      for (int k = 0; k < 64; ++k){ const float v = h_s[k][t]; s += v; q += v * v; }
      const float mu = s * (1.f / 64.f);
      mu_s[t] = mu;
      rs_s[t] = rsqrtf(q * (1.f / 64.f) - mu * mu + LN_EPS);
    }
    __syncthreads();
    for (int i = t; i < 32 * 64; i += 256){
      const int k = i >> 5, n = i & 31;
      h_s[k][n] = (h_s[k][n] - mu_s[n]) * rs_s[n] * lg_s[k] + lb_s[k];  // no ReLU
    }
    __syncthreads();

    float ar[2][4] = {{0}}, az[2][4] = {{0}}, an[2][4] = {{0}};
    #pragma unroll 4
    for (int k = 0; k < 64; ++k){
      union { uint2 u; __half2 h2[2]; } R, Z, N_;
      R.u  = *(const uint2*)&wT[k * WTS + c0];
      Z.u  = *(const uint2*)&wT[k * WTS + 64 + c0];
      N_.u = *(const uint2*)&wT[k * WTS + 128 + c0];
      const float2 r01 = __half22float2(R.h2[0]),  r23 = __half22float2(R.h2[1]);
      const float2 z01 = __half22float2(Z.h2[0]),  z23 = __half22float2(Z.h2[1]);
      const float2 n01 = __half22float2(N_.h2[0]), n23 = __half22float2(N_.h2[1]);
      const float h0v = h_s[k][gg * 2];
      const float h1v = h_s[k][gg * 2 + 1];
      ar[0][0] = fmaf(h0v, r01.x, ar[0][0]); ar[0][1] = fmaf(h0v, r01.y, ar[0][1]);
      ar[0][2] = fmaf(h0v, r23.x, ar[0][2]); ar[0][3] = fmaf(h0v, r23.y, ar[0][3]);
      az[0][0] = fmaf(h0v, z01.x, az[0][0]); az[0][1] = fmaf(h0v, z01.y, az[0][1]);
      az[0][2] = fmaf(h0v, z23.x, az[0][2]); az[0][3] = fmaf(h0v, z23.y, az[0][3]);
      an[0][0] = fmaf(h0v, n01.x, an[0][0]); an[0][1] = fmaf(h0v, n01.y, an[0][1]);
      an[0][2] = fmaf(h0v, n23.x, an[0][2]); an[0][3] = fmaf(h0v, n23.y, an[0][3]);
      ar[1][0] = fmaf(h1v, r01.x, ar[1][0]); ar[1][1] = fmaf(h1v, r01.y, ar[1][1]);
      ar[1][2] = fmaf(h1v, r23.x, ar[1][2]); ar[1][3] = fmaf(h1v, r23.y, ar[1][3]);
      az[1][0] = fmaf(h1v, z01.x, az[1][0]); az[1][1] = fmaf(h1v, z01.y, az[1][1]);
      az[1][2] = fmaf(h1v, z23.x, az[1][2]); az[1][3] = fmaf(h1v, z23.y, az[1][3]);
      an[1][0] = fmaf(h1v, n01.x, an[1][0]); an[1][1] = fmaf(h1v, n01.y, an[1][1]);
      an[1][2] = fmaf(h1v, n23.x, an[1][2]); an[1][3] = fmaf(h1v, n23.y, an[1][3]);
    }

    #pragma unroll
    for (int j = 0; j < 2; ++j){
      const int nj = tile + gg * 2 + j;
      if (nj < NN){
        float tv[4];
        #pragma unroll
        for (int i = 0; i < 4; ++i){
          const int c = c0 + i;
          const float r  = sigf(ar[j][i] + bi_s[c] + bh_s[c]);
          const float zz = sigf(az[j][i] + bi_s[64 + c] + bh_s[64 + c]);
          const float cd = tanhf(an[j][i] + bi_s[128 + c] + r * bh_s[128 + c]);
          tv[i] = (1.f - zz) * cd;
        }
        float4 o; o.x = tv[0]; o.y = tv[1]; o.z = tv[2]; o.w = tv[3];
        *(float4*)&tmp[(size_t)nj * 64 + c0] = o;
      }
    }
  }
}

// ---------------- decoder: [temporal, x] -> 64 -> 32 -> 2, clip ----------------

__global__ __launch_bounds__(256) void k_dec(const float* __restrict__ tmp,
    const float* __restrict__ x, const float* __restrict__ d0w,
    const float* __restrict__ d0b, const float* __restrict__ d1w,
    const float* __restrict__ d1b, const float* __restrict__ d2w,
    const float* __restrict__ d2b, float* __restrict__ out){
  __shared__ __half w0s[80 * 64];
  __shared__ __half w1s[64 * 32];
  __shared__ float w2s[64];
  __shared__ float b0s[64], b1s[32], b2s[2];
  __shared__ float dc[80][34];
  __shared__ float t0s[64][34];
  __shared__ float t1s[32][34];
  const int t = threadIdx.x;
  for (int i = t; i < 80 * 64; i += 256) w0s[i] = __float2half(d0w[i]);
  for (int i = t; i < 64 * 32; i += 256) w1s[i] = __float2half(d1w[i]);
  if (t < 64) w2s[t] = d2w[t];
  if (t < 64) b0s[t] = d0b[t];
  if (t < 32) b1s[t] = d1b[t];
  if (t < 2)  b2s[t] = d2b[t];

  for (int tile = blockIdx.x * 32; tile < NN; tile += gridDim.x * 32){
    __syncthreads();
    for (int i = t; i < 32 * 64; i += 256){
      int nidx = i >> 6, k = i & 63;
      int nn = tile + nidx;
      dc[k][nidx] = (nn < NN) ? tmp[(size_t)nn * 64 + k] : 0.f;
    }
    for (int i = t; i < 32 * 16; i += 256){
      int nidx = i >> 4, k = i & 15;
      int nn = tile + nidx;
      dc[64 + k][nidx] = (nn < NN) ? x[nn * IND + k] : 0.f;
    }
    __syncthreads();

    {
      const int col = t & 15, gg = t >> 4, c0 = col * 4;
      float a[2][4] = {{0}};
      #pragma unroll 4
      for (int k = 0; k < 80; ++k){
        union { uint2 u; __half2 h2[2]; } W;
        W.u = *(const uint2*)&w0s[k * 64 + c0];
        const float2 w01 = __half22float2(W.h2[0]), w23 = __half22float2(W.h2[1]);
        const float b0v = dc[k][gg * 2];
        const float b1v = dc[k][gg * 2 + 1];
        a[0][0] = fmaf(b0v, w01.x, a[0][0]); a[0][1] = fmaf(b0v, w01.y, a[0][1]);
        a[0][2] = fmaf(b0v, w23.x, a[0][2]); a[0][3] = fmaf(b0v, w23.y, a[0][3]);
        a[1][0] = fmaf(b1v, w01.x, a[1][0]); a[1][1] = fmaf(b1v, w01.y, a[1][1]);
        a[1][2] = fmaf(b1v, w23.x, a[1][2]); a[1][3] = fmaf(b1v, w23.y, a[1][3]);
      }
      #pragma unroll
      for (int j = 0; j < 2; ++j)
        #pragma unroll
        for (int i = 0; i < 4; ++i)
          t0s[c0 + i][gg * 2 + j] = fmaxf(a[j][i] + b0s[c0 + i], 0.f);
    }
    __syncthreads();

    {
      const int c1 = (t & 7) * 4, g1 = t >> 3;
      float a[4] = {0, 0, 0, 0};
      #pragma unroll 4
      for (int k = 0; k < 64; ++k){
        union { uint2 u; __half2 h2[2]; } W;
        W.u = *(const uint2*)&w1s[k * 32 + c1];
        const float2 w01 = __half22float2(W.h2[0]), w23 = __half22float2(W.h2[1]);
        const float bv = t0s[k][g1];
        a[0] = fmaf(bv, w01.x, a[0]); a[1] = fmaf(bv, w01.y, a[1]);
        a[2] = fmaf(bv, w23.x, a[2]); a[3] = fmaf(bv, w23.y, a[3]);
      }
      #pragma unroll
      for (int i = 0; i < 4; ++i)
        t1s[c1 + i][g1] = fmaxf(a[i] + b1s[c1 + i], 0.f);
    }
    __syncthreads();

    if (t < 64){
      const int nidx = t >> 1, o = t & 1;
      float a = b2s[o];
      #pragma unroll
      for (int k = 0; k < 32; ++k) a = fmaf(t1s[k][nidx], w2s[k * 2 + o], a);
      const int nn = tile + nidx;
      if (nn < NN) out[nn * 2 + o] = fminf(fmaxf(a, -0.5f), 0.5f);
    }
  }
}

// ---------------- launch ----------------

extern "C" void kernel_launch(void* const* d_in, const int* in_sizes, int n_in,
                              void* d_out, int out_size, void* d_ws, size_t ws_size,
                              hipStream_t stream){
  (void)in_sizes; (void)n_in; (void)out_size; (void)ws_size;
  const float* x      = (const float*)d_in[0];
  const int*   ei     = (const int*)d_in[1];
  const float* w0     = (const float*)d_in[2];
  const float* as0    = (const float*)d_in[3];
  const float* ad0    = (const float*)d_in[4];
  const float* b0     = (const float*)d_in[5];
  const float* ln0g   = (const float*)d_in[6];
  const float* ln0b   = (const float*)d_in[7];
  const float* w1     = (const float*)d_in[8];
  const float* as1    = (const float*)d_in[9];
  const float* ad1    = (const float*)d_in[10];
  const float* b1     = (const float*)d_in[11];
  const float* ln1g   = (const float*)d_in[12];
  const float* ln1b   = (const float*)d_in[13];
  const float* wih    = (const float*)d_in[14];
  // d_in[15] = gru_w_hh: unused (h0 == 0)
  const float* bih    = (const float*)d_in[16];
  const float* bhh    = (const float*)d_in[17];
  const float* d0w    = (const float*)d_in[18];
  const float* d0b    = (const float*)d_in[19];
  const float* d1w    = (const float*)d_in[20];
  const float* d1b    = (const float*)d_in[21];
  const float* d2w    = (const float*)d_in[22];
  const float* d2b    = (const float*)d_in[23];
  float* outp = (float*)d_out;

  char* ws = (char*)d_ws;
  size_t o = 0;
  auto alloc = [&](size_t bytes) -> char* {
    char* r = ws + o;
    o += (bytes + 255) & ~(size_t)255;
    return r;
  };
  int*            deg   = (int*)           alloc(NN * sizeof(int));
  unsigned short* colE  = (unsigned short*)alloc((size_t)NN * ELLW * sizeof(unsigned short));
  float*          es    = (float*)         alloc((size_t)NN * 4 * sizeof(float));
  float*          ed    = (float*)         alloc((size_t)NN * 4 * sizeof(float));
  __half*         xphP  = (__half*)        alloc((size_t)NN * CH * sizeof(__half));  // [8][NN][32]
  float*          hbufP = (float*)         alloc((size_t)NN * HID * sizeof(float));  // [8][NN][8]
  float*          tmp   = (float*)         alloc((size_t)NN * HID * sizeof(float));

  hipMemsetAsync(deg, 0, NN * sizeof(int), stream);
  k_build_proj1<<<PB + 8 * EB, 256, 0, stream>>>(ei, deg, colE, x, w0, as0, ad0,
                                                 xphP, es, ed);
  k_agg<<<AGB, 256, 0, stream>>>(xphP, (const float4*)es, (const float4*)ed,
                                 deg, colE, b0, hbufP);
  k_proj2<<<PB, 256, 0, stream>>>(hbufP, w1, as1, ad1, ln0g, ln0b, xphP, es, ed);
  k_agg<<<AGB, 256, 0, stream>>>(xphP, (const float4*)es, (const float4*)ed,
                                 deg, colE, b1, hbufP);
  k_gru<<<(NN + 31) / 32, 256, 0, stream>>>(hbufP, ln1g, ln1b, wih, bih, bhh, tmp);
  k_dec<<<(NN + 31) / 32, 256, 0, stream>>>(tmp, x, d0w, d0b, d1w, d1b, d2w, d2b,
                                            outp);
}

// Round 17
// 287.703 us; speedup vs baseline: 2.1340x; 2.1340x over previous
//
#include <hip/hip_runtime.h>
#include <hip/hip_fp16.h>
#include <math.h>

#define NN 50000
#define NE 800000
#define ETOT (NE + NN)
#define HID 64
#define CH 256          // HEADS*HID
#define IND 16
#define LN_EPS 1e-5f
#define NSLOPE 0.2f
#define ELLW 64         // ELL width; max in-deg for Poisson(17) graph << 64
#define EB ((ETOT + 255) / 256)   // edge chunks
#define PB ((NN + 31) / 32)       // proj1 tile blocks

__device__ __forceinline__ float lrelu(float v){ return v > 0.f ? v : NSLOPE * v; }
__device__ __forceinline__ float sigf(float v){ return 1.f / (1.f + __expf(-v)); }

// ---------------- fused projection-1 + XCD-partitioned ELL build ----------------
// blocks [0,PB): proj1 tile (K=IND): xp(fp16) = x @ w0, + fp32 logits
// blocks [PB,PB+8*EB): partitioned ELL scatter; block bb: partition bb&7,
//   chunk bb>>3; commit only edges with (dst&7)==partition. Round-robin
//   blockIdx->XCD => one XCD owns each node's colE lines (no 8x dirty-line
//   eviction amplification). src is loaded only after the filter passes.

__global__ __launch_bounds__(256) void k_build_proj1(const int* __restrict__ ei,
    int* __restrict__ deg, unsigned short* __restrict__ colE,
    const float* __restrict__ h, const float* __restrict__ w,
    const float* __restrict__ asr, const float* __restrict__ adr,
    __half* __restrict__ xph, float* __restrict__ es, float* __restrict__ ed){
  __shared__ float w_s[IND * CH];       // 16 KB
  __shared__ float h_s[IND][36];
  __shared__ float as_s[CH], ad_s[CH];
  const int t = threadIdx.x;

  if (blockIdx.x >= PB){
    // ---- ELL build path (XCD-partitioned by dst&7) ----
    const int bb = blockIdx.x - PB;
    const int part = bb & 7;
    const int e = (bb >> 3) * 256 + t;
    if (e < ETOT){
      const int d = (e < NE) ? ei[NE + e] : (e - NE);
      if ((d & 7) == part){
        const int s = (e < NE) ? ei[e] : d;   // src load only when committing
        const int slot = atomicAdd(&deg[d], 1);
        if (slot < ELLW) colE[d * ELLW + slot] = (unsigned short)s;
      }
    }
    return;
  }

  // ---- proj1 path (one 32-node tile per block) ----
  const int tile = blockIdx.x * 32;
  for (int i = t; i < IND * CH; i += 256) w_s[i] = w[i];
  as_s[t] = asr[t]; ad_s[t] = adr[t];
  for (int i = t; i < 32 * IND; i += 256){
    int n = i / IND, k = i % IND;
    int nn = tile + n;
    h_s[k][n] = (nn < NN) ? h[nn * IND + k] : 0.f;
  }
  __syncthreads();

  const int wv = t >> 6, l = t & 63;
  const int tc = l & 31, th = l >> 5;
  const int g = wv * 2 + th;
  const int c0 = tc * 4;
  const int hA = tc >> 4;

  float acc[4][8];
  #pragma unroll
  for (int j = 0; j < 4; ++j)
    #pragma unroll
    for (int i = 0; i < 8; ++i) acc[j][i] = 0.f;

  #pragma unroll 4
  for (int k = 0; k < IND; ++k){
    const float4 wa = *(const float4*)&w_s[k * CH + c0];
    const float4 wb = *(const float4*)&w_s[k * CH + c0 + 128];
    const float4 hv = *(const float4*)&h_s[k][g * 4];
    const float hj0 = hv.x, hj1 = hv.y, hj2 = hv.z, hj3 = hv.w;
    #define STEP(j, hjv) \
      acc[j][0] = fmaf(hjv, wa.x, acc[j][0]); \
      acc[j][1] = fmaf(hjv, wa.y, acc[j][1]); \
      acc[j][2] = fmaf(hjv, wa.z, acc[j][2]); \
      acc[j][3] = fmaf(hjv, wa.w, acc[j][3]); \
      acc[j][4] = fmaf(hjv, wb.x, acc[j][4]); \
      acc[j][5] = fmaf(hjv, wb.y, acc[j][5]); \
      acc[j][6] = fmaf(hjv, wb.z, acc[j][6]); \
      acc[j][7] = fmaf(hjv, wb.w, acc[j][7]);
    STEP(0, hj0) STEP(1, hj1) STEP(2, hj2) STEP(3, hj3)
    #undef STEP
  }

  #pragma unroll
  for (int j = 0; j < 4; ++j){
    const int nj = tile + g * 4 + j;
    float pa = 0.f, pb = 0.f, qa = 0.f, qb = 0.f;
    #pragma unroll
    for (int i = 0; i < 4; ++i){
      pa = fmaf(acc[j][i],     as_s[c0 + i],       pa);
      pb = fmaf(acc[j][4 + i], as_s[c0 + 128 + i], pb);
      qa = fmaf(acc[j][i],     ad_s[c0 + i],       qa);
      qb = fmaf(acc[j][4 + i], ad_s[c0 + 128 + i], qb);
    }
    #pragma unroll
    for (int d = 8; d; d >>= 1){
      pa += __shfl_xor(pa, d); pb += __shfl_xor(pb, d);
      qa += __shfl_xor(qa, d); qb += __shfl_xor(qb, d);
    }
    if (nj < NN){
      union { uint2 u; __half2 h2[2]; } oA, oB;
      oA.h2[0] = __float22half2_rn(make_float2(acc[j][0], acc[j][1]));
      oA.h2[1] = __float22half2_rn(make_float2(acc[j][2], acc[j][3]));
      oB.h2[0] = __float22half2_rn(make_float2(acc[j][4], acc[j][5]));
      oB.h2[1] = __float22half2_rn(make_float2(acc[j][6], acc[j][7]));
      *(uint2*)&xph[(size_t)nj * CH + c0]       = oA.u;
      *(uint2*)&xph[(size_t)nj * CH + c0 + 128] = oB.u;
      if ((tc & 15) == 0){
        es[nj * 4 + hA]     = pa;
        es[nj * 4 + hA + 2] = pb;
        ed[nj * 4 + hA]     = qa;
        ed[nj * 4 + hA + 2] = qb;
      }
    }
  }
}

// ---------------- projection-2: xp(fp16) = h @ W, fp16 LDS weights ----------------

template<int K, bool WHALF>
__global__ __launch_bounds__(256) void k_proj(const float* __restrict__ h,
    const float* __restrict__ w, const float* __restrict__ asr,
    const float* __restrict__ adr, __half* __restrict__ xph,
    float* __restrict__ es, float* __restrict__ ed){
  __shared__ float  w_sf[WHALF ? 1 : K * CH];
  __shared__ __half w_sh[WHALF ? K * CH : 1];
  __shared__ float h_s[K][36];
  __shared__ float as_s[CH], ad_s[CH];
  const int t = threadIdx.x;
  if (WHALF){
    for (int i = t; i < K * CH; i += 256) w_sh[i] = __float2half(w[i]);
  } else {
    for (int i = t; i < K * CH; i += 256) w_sf[i] = w[i];
  }
  as_s[t] = asr[t]; ad_s[t] = adr[t];
  const int wv = t >> 6, l = t & 63;
  const int tc = l & 31, th = l >> 5;
  const int g = wv * 2 + th;
  const int c0 = tc * 4;
  const int hA = tc >> 4;

  for (int tile = blockIdx.x * 32; tile < NN; tile += gridDim.x * 32){
    __syncthreads();
    for (int i = t; i < 32 * K; i += 256){
      int n = i / K, k = i % K;
      int nn = tile + n;
      h_s[k][n] = (nn < NN) ? h[nn * K + k] : 0.f;
    }
    __syncthreads();

    float acc[4][8];
    #pragma unroll
    for (int j = 0; j < 4; ++j)
      #pragma unroll
      for (int i = 0; i < 8; ++i) acc[j][i] = 0.f;

    #pragma unroll 4
    for (int k = 0; k < K; ++k){
      float4 wa, wb;
      if (WHALF){
        union { uint2 u; __half2 h2[2]; } A, B;
        A.u = *(const uint2*)&w_sh[k * CH + c0];
        B.u = *(const uint2*)&w_sh[k * CH + c0 + 128];
        const float2 a01 = __half22float2(A.h2[0]), a23 = __half22float2(A.h2[1]);
        const float2 b01 = __half22float2(B.h2[0]), b23 = __half22float2(B.h2[1]);
        wa.x = a01.x; wa.y = a01.y; wa.z = a23.x; wa.w = a23.y;
        wb.x = b01.x; wb.y = b01.y; wb.z = b23.x; wb.w = b23.y;
      } else {
        wa = *(const float4*)&w_sf[k * CH + c0];
        wb = *(const float4*)&w_sf[k * CH + c0 + 128];
      }
      const float4 hv = *(const float4*)&h_s[k][g * 4];
      const float hj0 = hv.x, hj1 = hv.y, hj2 = hv.z, hj3 = hv.w;
      #define STEP(j, hjv) \
        acc[j][0] = fmaf(hjv, wa.x, acc[j][0]); \
        acc[j][1] = fmaf(hjv, wa.y, acc[j][1]); \
        acc[j][2] = fmaf(hjv, wa.z, acc[j][2]); \
        acc[j][3] = fmaf(hjv, wa.w, acc[j][3]); \
        acc[j][4] = fmaf(hjv, wb.x, acc[j][4]); \
        acc[j][5] = fmaf(hjv, wb.y, acc[j][5]); \
        acc[j][6] = fmaf(hjv, wb.z, acc[j][6]); \
        acc[j][7] = fmaf(hjv, wb.w, acc[j][7]);
      STEP(0, hj0) STEP(1, hj1) STEP(2, hj2) STEP(3, hj3)
      #undef STEP
    }

    #pragma unroll
    for (int j = 0; j < 4; ++j){
      const int nj = tile + g * 4 + j;
      float pa = 0.f, pb = 0.f, qa = 0.f, qb = 0.f;
      #pragma unroll
      for (int i = 0; i < 4; ++i){
        pa = fmaf(acc[j][i],     as_s[c0 + i],       pa);
        pb = fmaf(acc[j][4 + i], as_s[c0 + 128 + i], pb);
        qa = fmaf(acc[j][i],     ad_s[c0 + i],       qa);
        qb = fmaf(acc[j][4 + i], ad_s[c0 + 128 + i], qb);
      }
      #pragma unroll
      for (int d = 8; d; d >>= 1){
        pa += __shfl_xor(pa, d); pb += __shfl_xor(pb, d);
        qa += __shfl_xor(qa, d); qb += __shfl_xor(qb, d);
      }
      if (nj < NN){
        union { uint2 u; __half2 h2[2]; } oA, oB;
        oA.h2[0] = __float22half2_rn(make_float2(acc[j][0], acc[j][1]));
        oA.h2[1] = __float22half2_rn(make_float2(acc[j][2], acc[j][3]));
        oB.h2[0] = __float22half2_rn(make_float2(acc[j][4], acc[j][5]));
        oB.h2[1] = __float22half2_rn(make_float2(acc[j][6], acc[j][7]));
        *(uint2*)&xph[(size_t)nj * CH + c0]       = oA.u;
        *(uint2*)&xph[(size_t)nj * CH + c0 + 128] = oB.u;
        if ((tc & 15) == 0){
          es[nj * 4 + hA]     = pa;
          es[nj * 4 + hA + 2] = pb;
          ed[nj * 4 + hA]     = qa;
          ed[nj * 4 + hA + 2] = qb;
        }
      }
    }
  }
}

// ---------------- fused GAT aggregate + head-mean + bias + LN (+ReLU) ----------------
// ELL edges (ushort): colE[n*64+j], j<deg[n]. 2 nodes per wave; lane owns 8 ch
// (uint4 gather); per-chunk weight LDS table. softmax max pass skipped
// (softmax(e-m)==softmax(e), logits O(0.5)).
// At fetch-path floor: each XCD must pull all of xph once (8 x 25.6 MB = 206 MB).

template<int DO_RELU>
__global__ __launch_bounds__(256) void k_agg(const __half* __restrict__ xph,
    const float4* __restrict__ es4, const float4* __restrict__ ed4,
    const int* __restrict__ deg, const unsigned short* __restrict__ colE,
    const float* __restrict__ bias, const float* __restrict__ lng,
    const float* __restrict__ lnb, float* __restrict__ hout){
  __shared__ float pbuf[4][2][32][4];   // [wave][half][edge][head] 4 KB
  const int wid = threadIdx.x >> 6, lane = threadIdx.x & 63;
  const int half = lane >> 5, l32 = lane & 31;
  const int n = blockIdx.x * 8 + wid * 2 + half;   // NN % 8 == 0: always valid
  const int head = l32 >> 3;
  const int c8 = l32 * 8;
  const int dg = deg[n];                // >= 1 (self-loop), <= 64
  const int dmax = max(dg, __shfl(dg, lane ^ 32));
  const float4 edn = ed4[n];
  float den = 0.f;
  float acc[8];
  #pragma unroll
  for (int i = 0; i < 8; ++i) acc[i] = 0.f;

  for (int base = 0; base < dmax; base += 32){
    const int cmax = min(dmax - base, 32);
    const int myS = (int)colE[n * ELLW + min(base + l32, dg - 1)];  // coalesced
    const float4 e = es4[myS];
    const bool act = (base + l32 < dg);
    float4 p4;
    p4.x = act ? __expf(lrelu(e.x + edn.x)) : 0.f;
    p4.y = act ? __expf(lrelu(e.y + edn.y)) : 0.f;
    p4.z = act ? __expf(lrelu(e.z + edn.z)) : 0.f;
    p4.w = act ? __expf(lrelu(e.w + edn.w)) : 0.f;
    *(float4*)&pbuf[wid][half][l32][0] = p4;   // wave-private, lockstep-safe
    const int sOff = myS * CH;

    for (int u0 = 0; u0 < cmax; u0 += 8){
      float pw[8]; uint4 xv[8];
      #pragma unroll
      for (int u = 0; u < 8; ++u){
        const int uu = u0 + u, us = uu & 31;
        const int so = __shfl(sOff, (lane & 32) + us);
        xv[u] = *(const uint4*)&xph[so + c8];
        pw[u] = (uu < cmax) ? pbuf[wid][half][us][head] : 0.f;
      }
      #pragma unroll
      for (int u = 0; u < 8; ++u){
        union { uint4 q; __half2 h2[4]; } cv; cv.q = xv[u];
        const float2 f0 = __half22float2(cv.h2[0]);
        const float2 f1 = __half22float2(cv.h2[1]);
        const float2 f2 = __half22float2(cv.h2[2]);
        const float2 f3 = __half22float2(cv.h2[3]);
        den += pw[u];
        acc[0] = fmaf(f0.x, pw[u], acc[0]); acc[1] = fmaf(f0.y, pw[u], acc[1]);
        acc[2] = fmaf(f1.x, pw[u], acc[2]); acc[3] = fmaf(f1.y, pw[u], acc[3]);
        acc[4] = fmaf(f2.x, pw[u], acc[4]); acc[5] = fmaf(f2.y, pw[u], acc[5]);
        acc[6] = fmaf(f3.x, pw[u], acc[6]); acc[7] = fmaf(f3.y, pw[u], acc[7]);
      }
    }
  }

  const float inv = 1.f / den;
  #pragma unroll
  for (int i = 0; i < 8; ++i) acc[i] *= inv;
  // head mean: lanes l32, l32^8, l32^16, l32^24 hold same 8 local channels
  #pragma unroll
  for (int i = 0; i < 8; ++i){
    acc[i] += __shfl_xor(acc[i], 8);
    acc[i] += __shfl_xor(acc[i], 16);
  }
  const int ch0 = (l32 & 7) * 8;
  const float4 bA = *(const float4*)&bias[ch0];
  const float4 bB = *(const float4*)&bias[ch0 + 4];
  acc[0] = acc[0]*0.25f + bA.x; acc[1] = acc[1]*0.25f + bA.y;
  acc[2] = acc[2]*0.25f + bA.z; acc[3] = acc[3]*0.25f + bA.w;
  acc[4] = acc[4]*0.25f + bB.x; acc[5] = acc[5]*0.25f + bB.y;
  acc[6] = acc[6]*0.25f + bB.z; acc[7] = acc[7]*0.25f + bB.w;
  // LayerNorm over 64 ch: 8 slots/lane x 8 lane-groups (xor 1,2,4)
  float s = 0.f, q = 0.f;
  #pragma unroll
  for (int i = 0; i < 8; ++i){ s += acc[i]; q += acc[i]*acc[i]; }
  #pragma unroll
  for (int d = 4; d; d >>= 1){ s += __shfl_xor(s, d); q += __shfl_xor(q, d); }
  const float mu = s * (1.f / 64.f);
  const float var = q * (1.f / 64.f) - mu * mu;
  const float rs = rsqrtf(var + LN_EPS);
  const float4 gA = *(const float4*)&lng[ch0];
  const float4 gB = *(const float4*)&lng[ch0 + 4];
  const float4 tA = *(const float4*)&lnb[ch0];
  const float4 tB = *(const float4*)&lnb[ch0 + 4];
  acc[0] = (acc[0]-mu)*rs*gA.x + tA.x; acc[1] = (acc[1]-mu)*rs*gA.y + tA.y;
  acc[2] = (acc[2]-mu)*rs*gA.z + tA.z; acc[3] = (acc[3]-mu)*rs*gA.w + tA.w;
  acc[4] = (acc[4]-mu)*rs*gB.x + tB.x; acc[5] = (acc[5]-mu)*rs*gB.y + tB.y;
  acc[6] = (acc[6]-mu)*rs*gB.z + tB.z; acc[7] = (acc[7]-mu)*rs*gB.w + tB.w;
  if (DO_RELU){
    #pragma unroll
    for (int i = 0; i < 8; ++i) acc[i] = fmaxf(acc[i], 0.f);
  }
  if (l32 < 8){
    float4 oA, oB;
    oA.x = acc[0]; oA.y = acc[1]; oA.z = acc[2]; oA.w = acc[3];
    oB.x = acc[4]; oB.y = acc[5]; oB.z = acc[6]; oB.w = acc[7];
    *(float4*)&hout[n * HID + l32 * 8]     = oA;
    *(float4*)&hout[n * HID + l32 * 8 + 4] = oB;
  }
}

// ---------------- GRU as register-blocked GEMM (h0 = 0), fp16 LDS weights ----------------

#define WTS 196   // wih^T LDS row stride in halves

__global__ __launch_bounds__(256) void k_gru(const float* __restrict__ h,
    const float* __restrict__ wih, const float* __restrict__ bih,
    const float* __restrict__ bhh, float* __restrict__ tmp){
  __shared__ __half wT[64 * WTS];       // [k][c<192] ~24.5 KB
  __shared__ float h_s[64][34];
  __shared__ float bi_s[192], bh_s[192];
  const int t = threadIdx.x;
  for (int i = t; i < 192 * 64; i += 256)
    wT[(i & 63) * WTS + (i >> 6)] = __float2half(wih[i]);
  if (t < 192){ bi_s[t] = bih[t]; bh_s[t] = bhh[t]; }
  const int col = t & 15, gg = t >> 4;
  const int c0 = col * 4;

  for (int tile = blockIdx.x * 32; tile < NN; tile += gridDim.x * 32){
    __syncthreads();
    for (int i = t; i < 32 * 64; i += 256){
      int nidx = i >> 6, k = i & 63;
      int nn = tile + nidx;
      h_s[k][nidx] = (nn < NN) ? h[nn * 64 + k] : 0.f;
    }
    __syncthreads();

    float ar[2][4] = {{0}}, az[2][4] = {{0}}, an[2][4] = {{0}};
    #pragma unroll 4
    for (int k = 0; k < 64; ++k){
      union { uint2 u; __half2 h2[2]; } R, Z, N_;
      R.u  = *(const uint2*)&wT[k * WTS + c0];
      Z.u  = *(const uint2*)&wT[k * WTS + 64 + c0];
      N_.u = *(const uint2*)&wT[k * WTS + 128 + c0];
      const float2 r01 = __half22float2(R.h2[0]),  r23 = __half22float2(R.h2[1]);
      const float2 z01 = __half22float2(Z.h2[0]),  z23 = __half22float2(Z.h2[1]);
      const float2 n01 = __half22float2(N_.h2[0]), n23 = __half22float2(N_.h2[1]);
      const float h0v = h_s[k][gg * 2];
      const float h1v = h_s[k][gg * 2 + 1];
      ar[0][0] = fmaf(h0v, r01.x, ar[0][0]); ar[0][1] = fmaf(h0v, r01.y, ar[0][1]);
      ar[0][2] = fmaf(h0v, r23.x, ar[0][2]); ar[0][3] = fmaf(h0v, r23.y, ar[0][3]);
      az[0][0] = fmaf(h0v, z01.x, az[0][0]); az[0][1] = fmaf(h0v, z01.y, az[0][1]);
      az[0][2] = fmaf(h0v, z23.x, az[0][2]); az[0][3] = fmaf(h0v, z23.y, az[0][3]);
      an[0][0] = fmaf(h0v, n01.x, an[0][0]); an[0][1] = fmaf(h0v, n01.y, an[0][1]);
      an[0][2] = fmaf(h0v, n23.x, an[0][2]); an[0][3] = fmaf(h0v, n23.y, an[0][3]);
      ar[1][0] = fmaf(h1v, r01.x, ar[1][0]); ar[1][1] = fmaf(h1v, r01.y, ar[1][1]);
      ar[1][2] = fmaf(h1v, r23.x, ar[1][2]); ar[1][3] = fmaf(h1v, r23.y, ar[1][3]);
      az[1][0] = fmaf(h1v, z01.x, az[1][0]); az[1][1] = fmaf(h1v, z01.y, az[1][1]);
      az[1][2] = fmaf(h1v, z23.x, az[1][2]); az[1][3] = fmaf(h1v, z23.y, az[1][3]);
      an[1][0] = fmaf(h1v, n01.x, an[1][0]); an[1][1] = fmaf(h1v, n01.y, an[1][1]);
      an[1][2] = fmaf(h1v, n23.x, an[1][2]); an[1][3] = fmaf(h1v, n23.y, an[1][3]);
    }

    #pragma unroll
    for (int j = 0; j < 2; ++j){
      const int nj = tile + gg * 2 + j;
      if (nj < NN){
        float tv[4];
        #pragma unroll
        for (int i = 0; i < 4; ++i){
          const int c = c0 + i;
          const float r  = sigf(ar[j][i] + bi_s[c] + bh_s[c]);
          const float zz = sigf(az[j][i] + bi_s[64 + c] + bh_s[64 + c]);
          const float cd = tanhf(an[j][i] + bi_s[128 + c] + r * bh_s[128 + c]);
          tv[i] = (1.f - zz) * cd;
        }
        float4 o; o.x = tv[0]; o.y = tv[1]; o.z = tv[2]; o.w = tv[3];
        *(float4*)&tmp[(size_t)nj * 64 + c0] = o;
      }
    }
  }
}

// ---------------- decoder: [temporal, x] -> 64 -> 32 -> 2, clip; fp16 LDS weights ----------------

__global__ __launch_bounds__(256) void k_dec(const float* __restrict__ tmp,
    const float* __restrict__ x, const float* __restrict__ d0w,
    const float* __restrict__ d0b, const float* __restrict__ d1w,
    const float* __restrict__ d1b, const float* __restrict__ d2w,
    const float* __restrict__ d2b, float* __restrict__ out){
  __shared__ __half w0s[80 * 64];       // 10 KB
  __shared__ __half w1s[64 * 32];       // 4 KB
  __shared__ float w2s[64];
  __shared__ float b0s[64], b1s[32], b2s[2];
  __shared__ float dc[80][34];
  __shared__ float t0s[64][34];
  __shared__ float t1s[32][34];
  const int t = threadIdx.x;
  for (int i = t; i < 80 * 64; i += 256) w0s[i] = __float2half(d0w[i]);
  for (int i = t; i < 64 * 32; i += 256) w1s[i] = __float2half(d1w[i]);
  if (t < 64) w2s[t] = d2w[t];
  if (t < 64) b0s[t] = d0b[t];
  if (t < 32) b1s[t] = d1b[t];
  if (t < 2)  b2s[t] = d2b[t];

  for (int tile = blockIdx.x * 32; tile < NN; tile += gridDim.x * 32){
    __syncthreads();
    for (int i = t; i < 32 * 64; i += 256){
      int nidx = i >> 6, k = i & 63;
      int nn = tile + nidx;
      dc[k][nidx] = (nn < NN) ? tmp[(size_t)nn * 64 + k] : 0.f;
    }
    for (int i = t; i < 32 * 16; i += 256){
      int nidx = i >> 4, k = i & 15;
      int nn = tile + nidx;
      dc[64 + k][nidx] = (nn < NN) ? x[nn * IND + k] : 0.f;
    }
    __syncthreads();

    // d0: 80 -> 64, ReLU
    {
      const int col = t & 15, gg = t >> 4, c0 = col * 4;
      float a[2][4] = {{0}};
      #pragma unroll 4
      for (int k = 0; k < 80; ++k){
        union { uint2 u; __half2 h2[2]; } W;
        W.u = *(const uint2*)&w0s[k * 64 + c0];
        const float2 w01 = __half22float2(W.h2[0]), w23 = __half22float2(W.h2[1]);
        const float b0v = dc[k][gg * 2];
        const float b1v = dc[k][gg * 2 + 1];
        a[0][0] = fmaf(b0v, w01.x, a[0][0]); a[0][1] = fmaf(b0v, w01.y, a[0][1]);
        a[0][2] = fmaf(b0v, w23.x, a[0][2]); a[0][3] = fmaf(b0v, w23.y, a[0][3]);
        a[1][0] = fmaf(b1v, w01.x, a[1][0]); a[1][1] = fmaf(b1v, w01.y, a[1][1]);
        a[1][2] = fmaf(b1v, w23.x, a[1][2]); a[1][3] = fmaf(b1v, w23.y, a[1][3]);
      }
      #pragma unroll
      for (int j = 0; j < 2; ++j)
        #pragma unroll
        for (int i = 0; i < 4; ++i)
          t0s[c0 + i][gg * 2 + j] = fmaxf(a[j][i] + b0s[c0 + i], 0.f);
    }
    __syncthreads();

    // d1: 64 -> 32, ReLU
    {
      const int c1 = (t & 7) * 4, g1 = t >> 3;
      float a[4] = {0, 0, 0, 0};
      #pragma unroll 4
      for (int k = 0; k < 64; ++k){
        union { uint2 u; __half2 h2[2]; } W;
        W.u = *(const uint2*)&w1s[k * 32 + c1];
        const float2 w01 = __half22float2(W.h2[0]), w23 = __half22float2(W.h2[1]);
        const float bv = t0s[k][g1];
        a[0] = fmaf(bv, w01.x, a[0]); a[1] = fmaf(bv, w01.y, a[1]);
        a[2] = fmaf(bv, w23.x, a[2]); a[3] = fmaf(bv, w23.y, a[3]);
      }
      #pragma unroll
      for (int i = 0; i < 4; ++i)
        t1s[c1 + i][g1] = fmaxf(a[i] + b1s[c1 + i], 0.f);
    }
    __syncthreads();

    // d2: 32 -> 2, clip
    if (t < 64){
      const int nidx = t >> 1, o = t & 1;
      float a = b2s[o];
      #pragma unroll
      for (int k = 0; k < 32; ++k) a = fmaf(t1s[k][nidx], w2s[k * 2 + o], a);
      const int nn = tile + nidx;
      if (nn < NN) out[nn * 2 + o] = fminf(fmaxf(a, -0.5f), 0.5f);
    }
  }
}

// ---------------- launch ----------------

extern "C" void kernel_launch(void* const* d_in, const int* in_sizes, int n_in,
                              void* d_out, int out_size, void* d_ws, size_t ws_size,
                              hipStream_t stream){
  (void)in_sizes; (void)n_in; (void)out_size; (void)ws_size;
  const float* x      = (const float*)d_in[0];
  const int*   ei     = (const int*)d_in[1];
  const float* w0     = (const float*)d_in[2];
  const float* as0    = (const float*)d_in[3];
  const float* ad0    = (const float*)d_in[4];
  const float* b0     = (const float*)d_in[5];
  const float* ln0g   = (const float*)d_in[6];
  const float* ln0b   = (const float*)d_in[7];
  const float* w1     = (const float*)d_in[8];
  const float* as1    = (const float*)d_in[9];
  const float* ad1    = (const float*)d_in[10];
  const float* b1     = (const float*)d_in[11];
  const float* ln1g   = (const float*)d_in[12];
  const float* ln1b   = (const float*)d_in[13];
  const float* wih    = (const float*)d_in[14];
  // d_in[15] = gru_w_hh: unused (h0 == 0)
  const float* bih    = (const float*)d_in[16];
  const float* bhh    = (const float*)d_in[17];
  const float* d0w    = (const float*)d_in[18];
  const float* d0b    = (const float*)d_in[19];
  const float* d1w    = (const float*)d_in[20];
  const float* d1b    = (const float*)d_in[21];
  const float* d2w    = (const float*)d_in[22];
  const float* d2b    = (const float*)d_in[23];
  float* outp = (float*)d_out;

  char* ws = (char*)d_ws;
  size_t o = 0;
  auto alloc = [&](size_t bytes) -> char* {
    char* r = ws + o;
    o += (bytes + 255) & ~(size_t)255;
    return r;
  };
  int*            deg  = (int*)           alloc(NN * sizeof(int));
  unsigned short* colE = (unsigned short*)alloc((size_t)NN * ELLW * sizeof(unsigned short)); // 6.4 MB
  float*          es   = (float*)         alloc((size_t)NN * 4 * sizeof(float));
  float*          ed   = (float*)         alloc((size_t)NN * 4 * sizeof(float));
  __half*         xph  = (__half*)        alloc((size_t)NN * CH * sizeof(__half));           // 25.6 MB
  float*          hbuf = (float*)         alloc((size_t)NN * HID * sizeof(float));           // 12.8 MB
  float*          tmp  = (float*)         alloc((size_t)NN * HID * sizeof(float));           // 12.8 MB

  hipMemsetAsync(deg, 0, NN * sizeof(int), stream);
  k_build_proj1<<<PB + 8 * EB, 256, 0, stream>>>(ei, deg, colE, x, w0, as0, ad0,
                                                 xph, es, ed);
  k_agg<1><<<NN / 8, 256, 0, stream>>>(xph, (const float4*)es, (const float4*)ed,
                                       deg, colE, b0, ln0g, ln0b, hbuf);
  k_proj<HID, true><<<(NN + 31) / 32, 256, 0, stream>>>(hbuf, w1, as1, ad1,
                                                        xph, es, ed);
  k_agg<0><<<NN / 8, 256, 0, stream>>>(xph, (const float4*)es, (const float4*)ed,
                                       deg, colE, b1, ln1g, ln1b, hbuf);
  k_gru<<<(NN + 31) / 32, 256, 0, stream>>>(hbuf, wih, bih, bhh, tmp);
  k_dec<<<(NN + 31) / 32, 256, 0, stream>>>(tmp, x, d0w, d0b, d1w, d1b, d2w, d2b,
                                            outp);
}